// Round 5
// baseline (222.576 us; speedup 1.0000x reference)
//
#include <hip/hip_runtime.h>

#define NA 8
#define NV 16
#define NS (NA * NV)          // 128 segments
#define NP 4                  // attribute pairs
#define NJ 256                // joint entries per pair (16*16)
#define NE (NP * NJ)          // 1024 joint entries total
#define FIX_SHIFT 43
#define FIX_MASK ((1ULL << FIX_SHIFT) - 1)
#define FIX_SCALE 2147483648.0f   // 2^31

// ---------------------------------------------------------------------------
// K1: DENSE loads. One float4/int4 (= half row) per LANE: consecutive lanes
// read consecutive 16B (4 lanes/cacheline, like the m13 copy pattern) instead
// of R4's 32B-stride pattern (2 lanes/line, 2x the line-split work).
// Row recombine: per_node = (my_half + shfl_xor(half,1)) / 8.
// Attr pairs split naturally: even lane holds attrs0-3 -> pair tables 0,1;
// odd lane holds attrs4-7 -> tables 2,3. Per-row atomic rate unchanged
// (proven irrelevant in R2-vs-R4 A/B anyway).
// nb=2048 -> 8 blocks/CU (64KB LDS) = 32 waves/CU, full occupancy.
// Overflow: rows/block <= 977 -> count < 2^21, sum < 977*2^31 < 2^41. OK.
// ---------------------------------------------------------------------------
__global__ __launch_bounds__(256) void k1_accum(
    const float4* __restrict__ preds4,         // [B*2]
    const int4*   __restrict__ attrs4,         // [B*2]
    unsigned long long* __restrict__ partials, // [nb, NE]
    int total4, int nb)
{
    __shared__ unsigned long long h[NE];   // 8 KB
    for (int i = threadIdx.x; i < NE; i += 256) h[i] = 0ULL;
    __syncthreads();

    const int pbase = (threadIdx.x & 1) ? 2 * NJ : 0;
    const int stride = nb * 256;
    for (int idx = blockIdx.x * 256 + threadIdx.x; idx < total4; idx += stride) {
        float4 p = preds4[idx];    // dense: lane i -> 16B at base + 16*i
        int4   a = attrs4[idx];

        float half = __builtin_amdgcn_rcpf(1.0f + __expf(-p.x))
                   + __builtin_amdgcn_rcpf(1.0f + __expf(-p.y))
                   + __builtin_amdgcn_rcpf(1.0f + __expf(-p.z))
                   + __builtin_amdgcn_rcpf(1.0f + __expf(-p.w));
        // lanes 2j,2j+1 hold the two halves of one row (total4 even, wave base
        // even -> pairs are both-active or both-inactive at the tail)
        float per_node = (half + __shfl_xor(half, 1)) * 0.125f;   // in (0,1)
        unsigned int fixed = (unsigned int)(per_node * FIX_SCALE);
        unsigned long long add = (1ULL << FIX_SHIFT) | (unsigned long long)fixed;

        // even lane: a = attrs[r][0..3] -> pairs (a01),(a23) = tables 0,1
        // odd  lane: a = attrs[r][4..7] -> pairs (a45),(a67) = tables 2,3
        atomicAdd(&h[pbase + ((a.x << 4) | a.y)], add);
        atomicAdd(&h[pbase + NJ + ((a.z << 4) | a.w)], add);
    }
    __syncthreads();

    unsigned long long* dst = partials + (size_t)blockIdx.x * NE;
    for (int i = threadIdx.x; i < NE; i += 256) {
        dst[i] = h[i];     // coalesced
    }
}

// ---------------------------------------------------------------------------
// K2a: group-reduce 8 consecutive block-tables (64KB contiguous, coalesced).
// Must UNPACK while accumulating (8 packed sums would overflow the 43-bit
// field). Output: separate u64 sum / u32 cnt tables, [n2, NE].
// ---------------------------------------------------------------------------
__global__ __launch_bounds__(256) void k2a_reduce(
    const unsigned long long* __restrict__ partials, // [nb, NE]
    unsigned long long* __restrict__ p2sum,          // [n2, NE]
    unsigned int*       __restrict__ p2cnt,          // [n2, NE]
    int g)                                           // blocks per group (8)
{
    const unsigned long long* src = partials + (size_t)blockIdx.x * g * NE;
    unsigned long long s0 = 0, s1 = 0, s2 = 0, s3 = 0;
    unsigned int c0 = 0, c1 = 0, c2 = 0, c3 = 0;
    for (int b = 0; b < g; ++b) {
        const unsigned long long* s = src + (size_t)b * NE;
        unsigned long long p0 = s[threadIdx.x];
        unsigned long long p1 = s[threadIdx.x + 256];
        unsigned long long p2 = s[threadIdx.x + 512];
        unsigned long long p3 = s[threadIdx.x + 768];
        s0 += p0 & FIX_MASK; c0 += (unsigned int)(p0 >> FIX_SHIFT);
        s1 += p1 & FIX_MASK; c1 += (unsigned int)(p1 >> FIX_SHIFT);
        s2 += p2 & FIX_MASK; c2 += (unsigned int)(p2 >> FIX_SHIFT);
        s3 += p3 & FIX_MASK; c3 += (unsigned int)(p3 >> FIX_SHIFT);
    }
    unsigned long long* ds = p2sum + (size_t)blockIdx.x * NE;
    unsigned int*       dc = p2cnt + (size_t)blockIdx.x * NE;
    ds[threadIdx.x] = s0; ds[threadIdx.x + 256] = s1;
    ds[threadIdx.x + 512] = s2; ds[threadIdx.x + 768] = s3;
    dc[threadIdx.x] = c0; dc[threadIdx.x + 256] = c1;
    dc[threadIdx.x + 512] = c2; dc[threadIdx.x + 768] = c3;
}

// ---------------------------------------------------------------------------
// K2b: one THREAD per joint entry (16 blocks x 64). Thread e sums column e
// over n2 tables — consecutive threads read consecutive addresses: coalesced.
// ---------------------------------------------------------------------------
__global__ __launch_bounds__(64) void k2b_reduce(
    const unsigned long long* __restrict__ p2sum,    // [n2, NE]
    const unsigned int*       __restrict__ p2cnt,    // [n2, NE]
    unsigned long long* __restrict__ jsum,           // [NE]
    unsigned int*       __restrict__ jcnt,           // [NE]
    int n2)
{
    const int e = blockIdx.x * 64 + threadIdx.x;
    unsigned long long S = 0; unsigned int C = 0;
    for (int j = 0; j < n2; ++j) {
        S += p2sum[(size_t)j * NE + e];
        C += p2cnt[(size_t)j * NE + e];
    }
    jsum[e] = S;
    jcnt[e] = C;
}

// ---------------------------------------------------------------------------
// K3: 1 block, 128 threads (one per segment). Marginalize joint tables to
// per-segment (sum,count), fp64 means + pairwise loss, scalar out.
// ---------------------------------------------------------------------------
__global__ __launch_bounds__(128) void k3_finalize(
    const unsigned long long* __restrict__ jsum,
    const unsigned int*       __restrict__ jcnt,
    float* __restrict__ out)
{
    __shared__ double s_mean[NS];
    __shared__ int    s_pres[NS];

    const int t = threadIdx.x;           // segment id
    const int a = t >> 4;                // attribute 0..7
    const int v = t & (NV - 1);          // value 0..15
    const int p = a >> 1;                // pair 0..3

    unsigned long long S = 0ULL;
    unsigned int C = 0u;
    if ((a & 1) == 0) {
        for (int j = 0; j < NV; ++j) {   // even attr = high nibble
            const int e = p * NJ + (v << 4) + j;
            S += jsum[e]; C += jcnt[e];
        }
    } else {
        for (int i = 0; i < NV; ++i) {   // odd attr = low nibble
            const int e = p * NJ + (i << 4) + v;
            S += jsum[e]; C += jcnt[e];
        }
    }
    s_pres[t] = (C > 0u) ? 1 : 0;
    s_mean[t] = (C > 0u)
        ? ((double)S * (1.0 / (double)FIX_SCALE)) / (double)C : 0.0;
    __syncthreads();

    double loss = 0.0;
    int    ncmp = 0;
    if (s_pres[t]) {
        const double mi = s_mean[t];
        for (int j = v + 1; j < NV; ++j) {
            const int sj = (a << 4) + j;
            if (s_pres[sj]) {
                const double d = mi - s_mean[sj];
                loss += d * d;
                ncmp += 1;
            }
        }
    }
    for (int off = 32; off > 0; off >>= 1) {
        loss += __shfl_down(loss, off, 64);
        ncmp += __shfl_down(ncmp, off, 64);
    }
    __shared__ double w_loss[2];
    __shared__ int    w_ncmp[2];
    const int wave = t >> 6;
    if ((t & 63) == 0) { w_loss[wave] = loss; w_ncmp[wave] = ncmp; }
    __syncthreads();
    if (t == 0) {
        const double total = w_loss[0] + w_loss[1];
        const int    n     = w_ncmp[0] + w_ncmp[1];
        out[0] = (n > 0) ? (float)(total / (double)n) : 0.0f;
    }
}

extern "C" void kernel_launch(void* const* d_in, const int* in_sizes, int n_in,
                              void* d_out, int out_size, void* d_ws, size_t ws_size,
                              hipStream_t stream) {
    const float4* preds4 = (const float4*)d_in[0];
    const int4*   attrs4 = (const int4*)d_in[1];
    float*        out    = (float*)d_out;

    const int B = in_sizes[1] / NA;
    const int total4 = B * 2;             // half-rows

    // ws: partials [nb,NE] u64 + p2sum [n2,NE] u64 + p2cnt [n2,NE] u32
    //     + jsum [NE] u64 + jcnt [NE] u32      (n2 = nb/8)
    auto need = [](int nb) -> size_t {
        int n2 = nb / 8;
        return (size_t)nb * NE * 8 + (size_t)n2 * NE * 12 + (size_t)NE * 12;
    };
    int nb = 2048;                        // 8 blocks/CU, full occupancy
    while (nb > 256 && need(nb) > ws_size) nb >>= 1;
    const int n2 = nb / 8;

    unsigned long long* partials = (unsigned long long*)d_ws;
    unsigned long long* p2sum = partials + (size_t)nb * NE;
    unsigned int*       p2cnt = (unsigned int*)(p2sum + (size_t)n2 * NE);
    unsigned long long* jsum  = (unsigned long long*)(p2cnt + (size_t)n2 * NE);
    unsigned int*       jcnt  = (unsigned int*)(jsum + NE);

    k1_accum<<<nb, 256, 0, stream>>>(preds4, attrs4, partials, total4, nb);
    k2a_reduce<<<n2, 256, 0, stream>>>(partials, p2sum, p2cnt, 8);
    k2b_reduce<<<NE / 64, 64, 0, stream>>>(p2sum, p2cnt, jsum, jcnt, n2);
    k3_finalize<<<1, 128, 0, stream>>>(jsum, jcnt, out);
}

// Round 6
// 161.161 us; speedup vs baseline: 1.3811x; 1.3811x over previous
//
#include <hip/hip_runtime.h>

#define NA 8
#define NV 16
#define NS (NA * NV)          // 128 segments
#define NP 4                  // attribute pairs
#define NJ 256                // joint entries per pair (16*16)
#define NE (NP * NJ)          // 1024 joint entries total
#define FIX_SHIFT 43
#define FIX_MASK ((1ULL << FIX_SHIFT) - 1)
#define FIX_SCALE 2147483648.0f   // 2^31

// ---------------------------------------------------------------------------
// K1 (unchanged from R5): dense float4/int4 loads, one half-row per lane,
// shfl_xor recombine, 2 packed ds_add_u64 per lane into pair-joint tables.
// nb=2048 -> 8 blocks/CU (64KB LDS), 32 waves/CU.
// Overflow: rows/block <= 977 -> count < 2^21, sum < 977*2^31 < 2^41. OK.
// ---------------------------------------------------------------------------
__global__ __launch_bounds__(256) void k1_accum(
    const float4* __restrict__ preds4,         // [B*2]
    const int4*   __restrict__ attrs4,         // [B*2]
    unsigned long long* __restrict__ partials, // [nb, NE]
    int total4, int nb)
{
    __shared__ unsigned long long h[NE];   // 8 KB
    for (int i = threadIdx.x; i < NE; i += 256) h[i] = 0ULL;
    __syncthreads();

    const int pbase = (threadIdx.x & 1) ? 2 * NJ : 0;
    const int stride = nb * 256;
    for (int idx = blockIdx.x * 256 + threadIdx.x; idx < total4; idx += stride) {
        float4 p = preds4[idx];    // dense: lane i -> 16B at base + 16*i
        int4   a = attrs4[idx];

        float half = __builtin_amdgcn_rcpf(1.0f + __expf(-p.x))
                   + __builtin_amdgcn_rcpf(1.0f + __expf(-p.y))
                   + __builtin_amdgcn_rcpf(1.0f + __expf(-p.z))
                   + __builtin_amdgcn_rcpf(1.0f + __expf(-p.w));
        float per_node = (half + __shfl_xor(half, 1)) * 0.125f;   // in (0,1)
        unsigned int fixed = (unsigned int)(per_node * FIX_SCALE);
        unsigned long long add = (1ULL << FIX_SHIFT) | (unsigned long long)fixed;

        atomicAdd(&h[pbase + ((a.x << 4) | a.y)], add);
        atomicAdd(&h[pbase + NJ + ((a.z << 4) | a.w)], add);
    }
    __syncthreads();

    unsigned long long* dst = partials + (size_t)blockIdx.x * NE;
    for (int i = threadIdx.x; i < NE; i += 256) {
        dst[i] = h[i];     // coalesced
    }
}

// ---------------------------------------------------------------------------
// K2 (replaces R5's k2a+k2b): 256 blocks x 256 threads. Block g reads tables
// [8g, 8g+8) — 64 KB contiguous, fully coalesced — unpacks into registers,
// then ONE u64 + ONE u32 global atomicAdd per entry. Atomic depth per
// address = nb/8 = 256, spread over 1024 addresses -> ~1-2 us tail.
// All-integer -> exact and deterministic under rocprof replay.
// (R5 lesson: a 16-wave kernel looping 256x over L3-latency data = 73 us.
//  This kernel has 1024 waves and an 8-iteration coalesced loop.)
// ---------------------------------------------------------------------------
__global__ __launch_bounds__(256) void k2_reduce(
    const unsigned long long* __restrict__ partials, // [nb, NE]
    unsigned long long* __restrict__ jsum,           // [NE] (pre-zeroed)
    unsigned int*       __restrict__ jcnt,           // [NE] (pre-zeroed)
    int g)                                           // tables per block (8)
{
    const unsigned long long* src = partials + (size_t)blockIdx.x * g * NE;
    unsigned long long s0 = 0, s1 = 0, s2 = 0, s3 = 0;
    unsigned int c0 = 0, c1 = 0, c2 = 0, c3 = 0;
    for (int b = 0; b < g; ++b) {
        const unsigned long long* s = src + (size_t)b * NE;
        unsigned long long p0 = s[threadIdx.x];
        unsigned long long p1 = s[threadIdx.x + 256];
        unsigned long long p2 = s[threadIdx.x + 512];
        unsigned long long p3 = s[threadIdx.x + 768];
        s0 += p0 & FIX_MASK; c0 += (unsigned int)(p0 >> FIX_SHIFT);
        s1 += p1 & FIX_MASK; c1 += (unsigned int)(p1 >> FIX_SHIFT);
        s2 += p2 & FIX_MASK; c2 += (unsigned int)(p2 >> FIX_SHIFT);
        s3 += p3 & FIX_MASK; c3 += (unsigned int)(p3 >> FIX_SHIFT);
    }
    atomicAdd(&jsum[threadIdx.x],       s0);
    atomicAdd(&jsum[threadIdx.x + 256], s1);
    atomicAdd(&jsum[threadIdx.x + 512], s2);
    atomicAdd(&jsum[threadIdx.x + 768], s3);
    atomicAdd(&jcnt[threadIdx.x],       c0);
    atomicAdd(&jcnt[threadIdx.x + 256], c1);
    atomicAdd(&jcnt[threadIdx.x + 512], c2);
    atomicAdd(&jcnt[threadIdx.x + 768], c3);
}

// ---------------------------------------------------------------------------
// K3: 1 block, 128 threads (one per segment). Marginalize joint tables to
// per-segment (sum,count), fp64 means + pairwise loss, scalar out.
// ---------------------------------------------------------------------------
__global__ __launch_bounds__(128) void k3_finalize(
    const unsigned long long* __restrict__ jsum,
    const unsigned int*       __restrict__ jcnt,
    float* __restrict__ out)
{
    __shared__ double s_mean[NS];
    __shared__ int    s_pres[NS];

    const int t = threadIdx.x;           // segment id
    const int a = t >> 4;                // attribute 0..7
    const int v = t & (NV - 1);          // value 0..15
    const int p = a >> 1;                // pair 0..3

    unsigned long long S = 0ULL;
    unsigned int C = 0u;
    if ((a & 1) == 0) {
        for (int j = 0; j < NV; ++j) {   // even attr = high nibble
            const int e = p * NJ + (v << 4) + j;
            S += jsum[e]; C += jcnt[e];
        }
    } else {
        for (int i = 0; i < NV; ++i) {   // odd attr = low nibble
            const int e = p * NJ + (i << 4) + v;
            S += jsum[e]; C += jcnt[e];
        }
    }
    s_pres[t] = (C > 0u) ? 1 : 0;
    s_mean[t] = (C > 0u)
        ? ((double)S * (1.0 / (double)FIX_SCALE)) / (double)C : 0.0;
    __syncthreads();

    double loss = 0.0;
    int    ncmp = 0;
    if (s_pres[t]) {
        const double mi = s_mean[t];
        for (int j = v + 1; j < NV; ++j) {
            const int sj = (a << 4) + j;
            if (s_pres[sj]) {
                const double d = mi - s_mean[sj];
                loss += d * d;
                ncmp += 1;
            }
        }
    }
    for (int off = 32; off > 0; off >>= 1) {
        loss += __shfl_down(loss, off, 64);
        ncmp += __shfl_down(ncmp, off, 64);
    }
    __shared__ double w_loss[2];
    __shared__ int    w_ncmp[2];
    const int wave = t >> 6;
    if ((t & 63) == 0) { w_loss[wave] = loss; w_ncmp[wave] = ncmp; }
    __syncthreads();
    if (t == 0) {
        const double total = w_loss[0] + w_loss[1];
        const int    n     = w_ncmp[0] + w_ncmp[1];
        out[0] = (n > 0) ? (float)(total / (double)n) : 0.0f;
    }
}

extern "C" void kernel_launch(void* const* d_in, const int* in_sizes, int n_in,
                              void* d_out, int out_size, void* d_ws, size_t ws_size,
                              hipStream_t stream) {
    const float4* preds4 = (const float4*)d_in[0];
    const int4*   attrs4 = (const int4*)d_in[1];
    float*        out    = (float*)d_out;

    const int B = in_sizes[1] / NA;
    const int total4 = B * 2;             // half-rows

    // ws: partials [nb,NE] u64  +  jsum [NE] u64  +  jcnt [NE] u32
    const size_t tail = (size_t)NE * (sizeof(unsigned long long) + sizeof(unsigned int));
    int nb = 2048;                        // 8 blocks/CU, full occupancy
    while (nb > 256 &&
           (size_t)nb * NE * sizeof(unsigned long long) + tail > ws_size) {
        nb >>= 1;
    }

    unsigned long long* partials = (unsigned long long*)d_ws;
    unsigned long long* jsum = partials + (size_t)nb * NE;
    unsigned int*       jcnt = (unsigned int*)(jsum + NE);

    hipMemsetAsync(jsum, 0, tail, stream);   // 12 KB, zero jsum+jcnt
    k1_accum<<<nb, 256, 0, stream>>>(preds4, attrs4, partials, total4, nb);
    k2_reduce<<<nb / 8, 256, 0, stream>>>(partials, jsum, jcnt, 8);
    k3_finalize<<<1, 128, 0, stream>>>(jsum, jcnt, out);
}

// Round 7
// 152.190 us; speedup vs baseline: 1.4625x; 1.0589x over previous
//
#include <hip/hip_runtime.h>

#define NA 8
#define NV 16
#define NS (NA * NV)          // 128 segments
#define NP 4                  // attribute pairs
#define NJ 256                // joint entries per pair (16*16)
#define NE (NP * NJ)          // 1024 joint entries total
#define FIX_SHIFT 43
#define FIX_MASK ((1ULL << FIX_SHIFT) - 1)
#define FIX_SCALE 2147483648.0f   // 2^31

// lane^1 pairwise add via DPP quad_perm [1,0,3,2] — VALU pipe, not LDS
// (keeps the recombine off the LDS queue that also serves the atomics)
__device__ __forceinline__ float xor1_add(float x) {
    int y = __builtin_amdgcn_mov_dpp(__float_as_int(x), 0xB1, 0xF, 0xF, true);
    return x + __int_as_float(y);
}

__device__ __forceinline__ void process_half(
    float4 p, int4 a, int pbase, unsigned long long* h)
{
    float halfsum = __builtin_amdgcn_rcpf(1.0f + __expf(-p.x))
                  + __builtin_amdgcn_rcpf(1.0f + __expf(-p.y))
                  + __builtin_amdgcn_rcpf(1.0f + __expf(-p.z))
                  + __builtin_amdgcn_rcpf(1.0f + __expf(-p.w));
    float per_node = xor1_add(halfsum) * 0.125f;   // in (0,1)
    unsigned int fixed = (unsigned int)(per_node * FIX_SCALE);
    unsigned long long add = (1ULL << FIX_SHIFT) | (unsigned long long)fixed;
    atomicAdd(&h[pbase + ((a.x << 4) | a.y)], add);
    atomicAdd(&h[pbase + NJ + ((a.z << 4) | a.w)], add);
}

// ---------------------------------------------------------------------------
// K1: R6 structure + 4x BATCHED loads. R2/R4/R6 A/B showed k1 pinned at
// ~43-46 us regardless of atomics (8/4/2), load pattern (strided/dense), and
// occupancy (31%/62%) -> hypothesis: per-wave MLP=2 outstanding loads is the
// gate (issue 2 loads -> waitcnt vmcnt(0) -> use). Here each loop pass issues
// 8 independent wave-dense loads (4 preds4 + 4 attrs4 at stride offsets)
// before any use: 8 KB in flight per wave, 4x MLP.
// Overflow @ nb=1024: rows/block <= 1954 -> count < 2^21, sum < 2^42. OK.
// ---------------------------------------------------------------------------
__global__ __launch_bounds__(256) void k1_accum(
    const float4* __restrict__ preds4,         // [B*2] half-rows
    const int4*   __restrict__ attrs4,         // [B*2]
    unsigned long long* __restrict__ partials, // [nb, NE]
    int total4, int nb)
{
    __shared__ unsigned long long h[NE];   // 8 KB
    for (int i = threadIdx.x; i < NE; i += 256) h[i] = 0ULL;
    __syncthreads();

    const int pbase = (threadIdx.x & 1) ? 2 * NJ : 0;
    const int stride  = nb * 256;
    const int stride4 = stride * 4;

    for (int base = blockIdx.x * 256 + threadIdx.x; base < total4; base += stride4) {
        const int i1 = base + stride;
        const int i2 = base + 2 * stride;
        const int i3 = base + 3 * stride;
        const bool b1 = i1 < total4, b2 = i2 < total4, b3 = i3 < total4;

        // issue all loads back-to-back (independent -> 8 outstanding)
        float4 p0 = preds4[base];
        int4   a0 = attrs4[base];
        float4 p1, p2, p3;
        int4   a1, a2, a3;
        if (b1) { p1 = preds4[i1]; a1 = attrs4[i1]; }
        if (b2) { p2 = preds4[i2]; a2 = attrs4[i2]; }
        if (b3) { p3 = preds4[i3]; a3 = attrs4[i3]; }

        process_half(p0, a0, pbase, h);
        if (b1) process_half(p1, a1, pbase, h);
        if (b2) process_half(p2, a2, pbase, h);
        if (b3) process_half(p3, a3, pbase, h);
    }
    __syncthreads();

    unsigned long long* dst = partials + (size_t)blockIdx.x * NE;
    for (int i = threadIdx.x; i < NE; i += 256) {
        dst[i] = h[i];     // coalesced
    }
}

// ---------------------------------------------------------------------------
// K2: 128 blocks x 256 threads. Block g reads tables [8g, 8g+8) — contiguous,
// coalesced — unpacks, accumulates in registers, one u64 + u32 global
// atomicAdd per entry (depth nb/8=128 per address over 1024 addresses).
// ---------------------------------------------------------------------------
__global__ __launch_bounds__(256) void k2_reduce(
    const unsigned long long* __restrict__ partials, // [nb, NE]
    unsigned long long* __restrict__ jsum,           // [NE] (pre-zeroed)
    unsigned int*       __restrict__ jcnt,           // [NE] (pre-zeroed)
    int g)
{
    const unsigned long long* src = partials + (size_t)blockIdx.x * g * NE;
    unsigned long long s0 = 0, s1 = 0, s2 = 0, s3 = 0;
    unsigned int c0 = 0, c1 = 0, c2 = 0, c3 = 0;
    for (int b = 0; b < g; ++b) {
        const unsigned long long* s = src + (size_t)b * NE;
        unsigned long long p0 = s[threadIdx.x];
        unsigned long long p1 = s[threadIdx.x + 256];
        unsigned long long p2 = s[threadIdx.x + 512];
        unsigned long long p3 = s[threadIdx.x + 768];
        s0 += p0 & FIX_MASK; c0 += (unsigned int)(p0 >> FIX_SHIFT);
        s1 += p1 & FIX_MASK; c1 += (unsigned int)(p1 >> FIX_SHIFT);
        s2 += p2 & FIX_MASK; c2 += (unsigned int)(p2 >> FIX_SHIFT);
        s3 += p3 & FIX_MASK; c3 += (unsigned int)(p3 >> FIX_SHIFT);
    }
    atomicAdd(&jsum[threadIdx.x],       s0);
    atomicAdd(&jsum[threadIdx.x + 256], s1);
    atomicAdd(&jsum[threadIdx.x + 512], s2);
    atomicAdd(&jsum[threadIdx.x + 768], s3);
    atomicAdd(&jcnt[threadIdx.x],       c0);
    atomicAdd(&jcnt[threadIdx.x + 256], c1);
    atomicAdd(&jcnt[threadIdx.x + 512], c2);
    atomicAdd(&jcnt[threadIdx.x + 768], c3);
}

// ---------------------------------------------------------------------------
// K3: 1 block, 128 threads (one per segment). Marginalize joint tables,
// fp64 means + pairwise loss, scalar out.
// ---------------------------------------------------------------------------
__global__ __launch_bounds__(128) void k3_finalize(
    const unsigned long long* __restrict__ jsum,
    const unsigned int*       __restrict__ jcnt,
    float* __restrict__ out)
{
    __shared__ double s_mean[NS];
    __shared__ int    s_pres[NS];

    const int t = threadIdx.x;           // segment id
    const int a = t >> 4;                // attribute 0..7
    const int v = t & (NV - 1);          // value 0..15
    const int p = a >> 1;                // pair 0..3

    unsigned long long S = 0ULL;
    unsigned int C = 0u;
    if ((a & 1) == 0) {
        for (int j = 0; j < NV; ++j) {   // even attr = high nibble
            const int e = p * NJ + (v << 4) + j;
            S += jsum[e]; C += jcnt[e];
        }
    } else {
        for (int i = 0; i < NV; ++i) {   // odd attr = low nibble
            const int e = p * NJ + (i << 4) + v;
            S += jsum[e]; C += jcnt[e];
        }
    }
    s_pres[t] = (C > 0u) ? 1 : 0;
    s_mean[t] = (C > 0u)
        ? ((double)S * (1.0 / (double)FIX_SCALE)) / (double)C : 0.0;
    __syncthreads();

    double loss = 0.0;
    int    ncmp = 0;
    if (s_pres[t]) {
        const double mi = s_mean[t];
        for (int j = v + 1; j < NV; ++j) {
            const int sj = (a << 4) + j;
            if (s_pres[sj]) {
                const double d = mi - s_mean[sj];
                loss += d * d;
                ncmp += 1;
            }
        }
    }
    for (int off = 32; off > 0; off >>= 1) {
        loss += __shfl_down(loss, off, 64);
        ncmp += __shfl_down(ncmp, off, 64);
    }
    __shared__ double w_loss[2];
    __shared__ int    w_ncmp[2];
    const int wave = t >> 6;
    if ((t & 63) == 0) { w_loss[wave] = loss; w_ncmp[wave] = ncmp; }
    __syncthreads();
    if (t == 0) {
        const double total = w_loss[0] + w_loss[1];
        const int    n     = w_ncmp[0] + w_ncmp[1];
        out[0] = (n > 0) ? (float)(total / (double)n) : 0.0f;
    }
}

extern "C" void kernel_launch(void* const* d_in, const int* in_sizes, int n_in,
                              void* d_out, int out_size, void* d_ws, size_t ws_size,
                              hipStream_t stream) {
    const float4* preds4 = (const float4*)d_in[0];
    const int4*   attrs4 = (const int4*)d_in[1];
    float*        out    = (float*)d_out;

    const int B = in_sizes[1] / NA;
    const int total4 = B * 2;             // half-rows

    // ws: partials [nb,NE] u64  +  jsum [NE] u64  +  jcnt [NE] u32
    const size_t tail = (size_t)NE * (sizeof(unsigned long long) + sizeof(unsigned int));
    int nb = 1024;                        // 4 blocks/CU; 15.3 iters/thread
    while (nb > 256 &&
           (size_t)nb * NE * sizeof(unsigned long long) + tail > ws_size) {
        nb >>= 1;
    }

    unsigned long long* partials = (unsigned long long*)d_ws;
    unsigned long long* jsum = partials + (size_t)nb * NE;
    unsigned int*       jcnt = (unsigned int*)(jsum + NE);

    hipMemsetAsync(jsum, 0, tail, stream);   // 12 KB
    k1_accum<<<nb, 256, 0, stream>>>(preds4, attrs4, partials, total4, nb);
    k2_reduce<<<nb / 8, 256, 0, stream>>>(partials, jsum, jcnt, 8);
    k3_finalize<<<1, 128, 0, stream>>>(jsum, jcnt, out);
}